// Round 1
// 145.361 us; speedup vs baseline: 1.0158x; 1.0158x over previous
//
#include <hip/hip_runtime.h>
#include <math.h>

// Problem constants (from reference): N=256, B=8, S=14, PILOTS=[0,7], U=1
static constexpr int kN   = 256;
static constexpr int kB   = 8;
static constexpr int kS   = 14;
static constexpr int kNSH = 12;   // S - len(PILOTS)
static constexpr int kBS  = kB * kS;  // 112

// Workspace layout: partial DFT sums, 4 n-quarters per (b,s):
//   wsR[q][bs][k], wsI[q][bs][k]  (q=0..3)
static constexpr int kWsPlane = 4 * kBS * kN;   // floats per plane

// ---------------------------------------------------------------------------
// Kernel 1: partial DFT. Each 64-thread (1-wave) block computes, for one
// (b,s), one n-quarter q (64 input samples) and one k-group kg (64 output
// bins):   Hpart[q][bs][k] = sum_{n in [64q,64q+64)} x[bs,n] * e^{-2pi i k n/N}
//
// Derivation (unchanged from the verified kernel): h_freq_est (pre-einsum)
// == fft(x, axis=-1) * conj(zc); the conj(zc) multiply and the quarter-sum
// are folded into kernel 2's prologue.
//
// Grid: 112*16 = 1792 one-wave blocks -> 7 waves/CU across ALL 256 CUs
// (vs 112 blocks / 44% of CUs / 1 wave/SIMD before), and the serial
// rotation chain shrinks 256 -> 64 iterations per thread.
// ---------------------------------------------------------------------------
__global__ __launch_bounds__(64) void dft_part_kernel(
    const float* __restrict__ xr, const float* __restrict__ xi,
    float* __restrict__ wsR, float* __restrict__ wsI)
{
    __shared__ float sxr[64];
    __shared__ float sxi[64];
    const int blk = blockIdx.x;
    const int bs  = blk >> 4;          // 0..111
    const int q   = (blk >> 2) & 3;    // n-quarter
    const int kg  = blk & 3;           // k-group
    const int l   = threadIdx.x;       // 0..63
    const int k   = kg * 64 + l;       // output bin

    // Stage this quarter's 64 input samples (coalesced 256B per plane)
    sxr[l] = xr[bs * kN + q * 64 + l];
    sxi[l] = xi[bs * kN + q * 64 + l];

    const float two_pi_over_N = 6.283185307179586476925f / (float)kN;
    float wi, wr;
    sincosf(-two_pi_over_N * (float)k, &wi, &wr);   // w = e^{-2*pi*i*k/N}

    __syncthreads();

    float Hr = 0.0f, Hi = 0.0f;

    #pragma unroll
    for (int c = 0; c < 2; ++c) {
        // exact integer phase reduction at the absolute n0 of this chunk:
        // cur = e^{-2*pi*i*((k*n0) mod N)/N}
        const int n0 = q * 64 + c * 32;
        const int p  = (k * n0) & (kN - 1);
        float ci, cr;
        sincosf(-two_pi_over_N * (float)p, &ci, &cr);
        #pragma unroll
        for (int j = 0; j < 32; ++j) {
            const float a = sxr[c * 32 + j];   // wave-uniform broadcast (free)
            const float b = sxi[c * 32 + j];
            Hr = fmaf(a, cr, fmaf(-b, ci, Hr));
            Hi = fmaf(a, ci, fmaf( b, cr, Hi));
            const float nr = cr * wr - ci * wi;
            const float ni = cr * wi + ci * wr;
            cr = nr; ci = ni;
        }
    }

    // coalesced partial write (summed + *conj(zc) in kernel 2's prologue)
    wsR[(q * kBS + bs) * kN + k] = Hr;
    wsI[(q * kBS + bs) * kN + k] = Hi;
}

// ---------------------------------------------------------------------------
// Kernel 2: out[b,s,n] = sum_m cov[c(b,s), n, m] * h[b,s,m]   (complex)
// where h = (sum_q Hpart[q]) * conj(zc), folded into the prologue.
// Output layout: PLANAR — real plane (B*S*N floats) then imag plane.
//
// Grid: 112*32 = 3584 one-wave (64-thread) blocks, 8 rows each ->
// EXACTLY 14 blocks per CU (perfect static balance; previous 896x4-wave
// grid gave 3.5 blocks/CU, a 4-vs-3 tail). No __syncthreads needed.
// The 16 long-latency HBM cov loads are issued first (16 KB in flight per
// wave, 224 KB/CU at 14 waves -- far above the ~9 KB BW*latency product);
// the L2-resident ws/zc prologue loads hide under them.
// ---------------------------------------------------------------------------
__global__ __launch_bounds__(64) void matvec_kernel(
    const float* __restrict__ covr, const float* __restrict__ covi,
    const float* __restrict__ wsR,  const float* __restrict__ wsI,
    const float* __restrict__ zcr,  const float* __restrict__ zci,
    const int*  __restrict__ shift, const int* __restrict__ gidx,
    float* __restrict__ out)
{
    const int bs = blockIdx.x >> 5;      // (b*S + s), 0..111
    const int r0 = (blockIdx.x & 31) * 8;  // first of this wave's 8 rows
    const int s  = bs % kS;
    const int b  = bs / kS;

    // complete[b,s]: padded-zero column 0 gathered; gidx==0 -> index 0,
    // else shift_val[b, gidx-1]
    const int g = gidx[s];
    const int c = (g == 0) ? 0 : shift[b * kNSH + (g - 1)];

    const int l = threadIdx.x;           // lane 0..63; lane owns m = 4l..4l+3

    const long base = (long)c * (long)(kN * kN);
    const float* __restrict__ rb = covr + base;
    const float* __restrict__ ib = covi + base;

    // Issue all 16 HBM loads before any compute (MLP)
    float4 mr[8], mi[8];
    #pragma unroll
    for (int r = 0; r < 8; ++r) {
        mr[r] = ((const float4*)(rb + (long)(r0 + r) * kN))[l];
        mi[r] = ((const float4*)(ib + (long)(r0 + r) * kN))[l];
    }

    // Prologue: sum the 4 DFT partials (L2-resident) and apply conj(zc)
    float4 Hr = make_float4(0.f, 0.f, 0.f, 0.f);
    float4 Hi = make_float4(0.f, 0.f, 0.f, 0.f);
    #pragma unroll
    for (int q = 0; q < 4; ++q) {
        const float4 pr = ((const float4*)(wsR + (q * kBS + bs) * kN))[l];
        const float4 pi = ((const float4*)(wsI + (q * kBS + bs) * kN))[l];
        Hr.x += pr.x; Hr.y += pr.y; Hr.z += pr.z; Hr.w += pr.w;
        Hi.x += pi.x; Hi.y += pi.y; Hi.z += pi.z; Hi.w += pi.w;
    }
    const float4 zr = ((const float4*)zcr)[l];
    const float4 zi = ((const float4*)zci)[l];
    float4 hr, hi;   // h = H * conj(zc)
    hr.x = fmaf(Hr.x, zr.x,  Hi.x * zi.x);  hi.x = fmaf(Hi.x, zr.x, -Hr.x * zi.x);
    hr.y = fmaf(Hr.y, zr.y,  Hi.y * zi.y);  hi.y = fmaf(Hi.y, zr.y, -Hr.y * zi.y);
    hr.z = fmaf(Hr.z, zr.z,  Hi.z * zi.z);  hi.z = fmaf(Hi.z, zr.z, -Hr.z * zi.z);
    hr.w = fmaf(Hr.w, zr.w,  Hi.w * zi.w);  hi.w = fmaf(Hi.w, zr.w, -Hr.w * zi.w);

    // 8 independent complex dot partials
    float ar[8], ai[8];
    #pragma unroll
    for (int r = 0; r < 8; ++r) {
        ar[r] = mr[r].x*hr.x + mr[r].y*hr.y + mr[r].z*hr.z + mr[r].w*hr.w
              - (mi[r].x*hi.x + mi[r].y*hi.y + mi[r].z*hi.z + mi[r].w*hi.w);
        ai[r] = mr[r].x*hi.x + mr[r].y*hi.y + mr[r].z*hi.z + mr[r].w*hi.w
              +  mi[r].x*hr.x + mi[r].y*hr.y + mi[r].z*hr.z + mi[r].w*hr.w;
    }

    // Butterfly reduce: outer loop = level, inner loop = 8 independent rows
    // (16 independent shuffle chains in flight per level)
    #pragma unroll
    for (int off = 32; off > 0; off >>= 1) {
        #pragma unroll
        for (int r = 0; r < 8; ++r) {
            ar[r] += __shfl_xor(ar[r], off, 64);
            ai[r] += __shfl_xor(ai[r], off, 64);
        }
    }

    if (l == 0) {
        #pragma unroll
        for (int r = 0; r < 8; ++r) {
            // PLANAR complex layout: [Re plane | Im plane]
            out[(long)bs * kN + r0 + r]                    = ar[r];
            out[(long)(kBS * kN) + (long)bs * kN + r0 + r] = ai[r];
        }
    }
}

extern "C" void kernel_launch(void* const* d_in, const int* in_sizes, int n_in,
                              void* d_out, int out_size, void* d_ws, size_t ws_size,
                              hipStream_t stream) {
    const float* xr    = (const float*)d_in[0];  // (B,S,N)
    const float* xi    = (const float*)d_in[1];  // (B,S,N)
    const float* covr  = (const float*)d_in[2];  // (N,N,N)
    const float* covi  = (const float*)d_in[3];  // (N,N,N)
    const float* zcr   = (const float*)d_in[4];  // (N,)
    const float* zci   = (const float*)d_in[5];  // (N,)
    const int*   shift = (const int*)d_in[6];    // (B, S-2)
    const int*   gidx  = (const int*)d_in[7];    // (S,)

    float* wsR = (float*)d_ws;                   // 4*112*256 floats
    float* wsI = wsR + kWsPlane;                 // 4*112*256 floats

    dft_part_kernel<<<kBS * 16, 64, 0, stream>>>(xr, xi, wsR, wsI);
    matvec_kernel<<<kBS * 32, 64, 0, stream>>>(covr, covi, wsR, wsI, zcr, zci,
                                               shift, gidx, (float*)d_out);
}